// Round 3
// baseline (493.281 us; speedup 1.0000x reference)
//
#include <hip/hip_runtime.h>
#include <hip/hip_bf16.h>

// ---------------------------------------------------------------------------
// Round 3: split kernels (focused = pure V projection, high occupancy;
// main = full attention, deep W-prefetch pipeline), coalesced LDS-staged
// epilogue, prologue X staging.
//   x:        (2,1024,64,512) f32
//   w_qkv:    (1536,512)      f32   (rows 0..511=Q, 512..1023=K, 1024..1535=V)
//   pos_bias: (8,64,64)       f32
//   mask:     (2,) bool/int
//   out:      (2,1024,64,512) f32
// ---------------------------------------------------------------------------

typedef __attribute__((ext_vector_type(4))) float f32x4;
typedef __attribute__((ext_vector_type(8))) short s16x8;

#define DIM 512

__device__ __forceinline__ short f2bf(float f) {
    unsigned int u = __builtin_bit_cast(unsigned int, f);
    u += 0x7fffu + ((u >> 16) & 1u);
    return (short)(u >> 16);
}

__device__ __forceinline__ int xaddr(int row, int kb) {   // X: 64x512 bf16, 1024B rows
    return (row << 10) + (kb ^ ((row & 7) << 4));
}
__device__ __forceinline__ int taddr(int row, int kb) {   // 64x64 bf16 tile, 128B rows
    return (row << 7) + (kb ^ ((row & 7) << 4));
}

// W pre-swizzle: 16B fragment chunk index = (rowblk*16 + ks)*64 + lane
// (wave's fragment load = one contiguous 1 KiB read). q-scale folded into Wq.
__global__ void conv_w(const float* __restrict__ w, unsigned short* __restrict__ wb) {
    int gid  = blockIdx.x * 256 + threadIdx.x;       // 0 .. 98303
    int lane = gid & 63;
    int ks   = (gid >> 6) & 15;
    int rowblk = gid >> 10;
    int row = rowblk * 16 + (lane & 15);
    int col = ks * 32 + (lane >> 4) * 8;
    const float* p = w + (size_t)row * DIM + col;
    float4 a = *(const float4*)p;
    float4 b = *(const float4*)(p + 4);
    float sc = (row < 512) ? 0.125f : 1.0f;
    s16x8 v;
    v[0] = f2bf(a.x * sc); v[1] = f2bf(a.y * sc);
    v[2] = f2bf(a.z * sc); v[3] = f2bf(a.w * sc);
    v[4] = f2bf(b.x * sc); v[5] = f2bf(b.y * sc);
    v[6] = f2bf(b.z * sc); v[7] = f2bf(b.w * sc);
    *(s16x8*)(wb + (size_t)gid * 8) = v;
}

template<int WB16>
__device__ __forceinline__ s16x8 wfragL(const unsigned short* __restrict__ wb,
                                        const float* __restrict__ w,
                                        int rowblk, int ks, int lane) {
    if constexpr (WB16) {
        return *(const s16x8*)(wb + ((size_t)(rowblk * 16 + ks) * 64 + lane) * 8);
    } else {
        int row = rowblk * 16 + (lane & 15);
        int col = ks * 32 + (lane >> 4) * 8;
        const float* p = w + (size_t)row * DIM + col;
        float4 u0 = *(const float4*)p;
        float4 u1 = *(const float4*)(p + 4);
        float sc = (row < 512) ? 0.125f : 1.0f;
        s16x8 v;
        v[0] = f2bf(u0.x * sc); v[1] = f2bf(u0.y * sc);
        v[2] = f2bf(u0.z * sc); v[3] = f2bf(u0.w * sc);
        v[4] = f2bf(u1.x * sc); v[5] = f2bf(u1.y * sc);
        v[6] = f2bf(u1.z * sc); v[7] = f2bf(u1.w * sc);
        return v;
    }
}

__device__ __forceinline__ bool decode_mask(const unsigned int* mk, int b) {
    unsigned int m0 = mk[0], m1 = mk[1];
    if (m0 <= 1u && m1 <= 1u) return ((b == 0) ? m0 : m1) != 0u;
    return ((const unsigned char*)mk)[b] != 0;
}

// ===========================================================================
// FOCUSED kernel: eye mask => attn = I => out = v = X . Wv^T.
// LDS: 2 x 8KB X chunk double-buffer + 64KB out staging = 80KB -> 2 blocks/CU.
// ===========================================================================
template<int WB16>
__global__ __launch_bounds__(512, 4)
void attn_focus(const float* __restrict__ x,
                const float* __restrict__ w,
                const unsigned short* __restrict__ wb,
                const unsigned int* __restrict__ mk,
                float* __restrict__ out)
{
    const int bs = blockIdx.x;
    const int b  = bs >> 10;
    if (!decode_mask(mk, b)) return;

    extern __shared__ char smem[];
    const int tid  = threadIdx.x;
    const int lane = tid & 63;
    const int wave = tid >> 6;          // head
    const int g    = lane >> 4;
    const int c    = lane & 15;

    const float* xblk   = x   + (size_t)bs * (64 * DIM);
    float*       outblk = out + (size_t)bs * (64 * DIM);
    char* stage = smem + 16384;
    const int RV = 64 + wave * 4;

    // X chunk staging: 64 rows x 64 cols f32 -> 8KB bf16 (taddr layout)
    auto fld = [&](int kk, float4 (&st)[2]) {
        const float* gp = xblk + (tid >> 3) * DIM + kk * 64 + (tid & 7) * 8;
        st[0] = *(const float4*)gp;
        st[1] = *(const float4*)(gp + 4);
    };
    auto fwr = [&](int p, float4 (&st)[2]) {
        int row = tid >> 3, cg = tid & 7;
        s16x8 v;
        v[0] = f2bf(st[0].x); v[1] = f2bf(st[0].y);
        v[2] = f2bf(st[0].z); v[3] = f2bf(st[0].w);
        v[4] = f2bf(st[1].x); v[5] = f2bf(st[1].y);
        v[6] = f2bf(st[1].z); v[7] = f2bf(st[1].w);
        *(s16x8*)(smem + p * 8192 + (row << 7) + ((cg * 16) ^ ((row & 7) << 4))) = v;
    };
    auto xfc = [&](s16x8 (&a)[4], int p, int ksl) {
        #pragma unroll
        for (int tc = 0; tc < 4; ++tc) {
            int row = tc * 16 + c;
            a[tc] = *(const s16x8*)(smem + p * 8192 + (row << 7) +
                                    ((ksl * 64 + g * 16) ^ ((row & 7) << 4)));
        }
    };
    auto wl = [&](s16x8 (&d)[4], int ks) {
        #pragma unroll
        for (int i = 0; i < 4; ++i) d[i] = wfragL<WB16>(wb, w, RV + i, ks, lane);
    };
    // va[tm][tn] = vT tile: A = Wv rows (dh), B = X rows (tokens)
    auto mmT = [&](f32x4 (&acc)[4][4], s16x8 (&a)[4], s16x8 (&bfr)[4]) {
        #pragma unroll
        for (int tr = 0; tr < 4; ++tr)
            #pragma unroll
            for (int tc = 0; tc < 4; ++tc)
                acc[tr][tc] = __builtin_amdgcn_mfma_f32_16x16x32_bf16(
                                  a[tr], bfr[tc], acc[tr][tc], 0, 0, 0);
    };

    f32x4 va[4][4];
    {
        f32x4 z = {0.f, 0.f, 0.f, 0.f};
        #pragma unroll
        for (int i = 0; i < 4; ++i)
            #pragma unroll
            for (int j = 0; j < 4; ++j) va[i][j] = z;
    }

    float4 sA[2], sB[2];
    s16x8 wf[4], af[4];

    fld(0, sA); fwr(0, sA);
    __syncthreads();

    #define FSTEP(kk, SN)                                              \
    {                                                                  \
        if ((kk) < 7) fld((kk) + 1, s##SN);                            \
        wl(wf, 2 * (kk));                                              \
        xfc(af, (kk) & 1, 0);                                          \
        mmT(va, wf, af);                                               \
        wl(wf, 2 * (kk) + 1);                                          \
        xfc(af, (kk) & 1, 1);                                          \
        mmT(va, wf, af);                                               \
        if ((kk) < 7) { fwr(((kk) + 1) & 1, s##SN); __syncthreads(); } \
    }
    FSTEP(0, B) FSTEP(1, A) FSTEP(2, B) FSTEP(3, A)
    FSTEP(4, B) FSTEP(5, A) FSTEP(6, B) FSTEP(7, A)
    #undef FSTEP

    // epilogue: va[tm][tn] holds vT[dh=16tm+4g+r][tok=16tn+c]; stage as
    // out rows (tokens) then linear coalesced store, 32 rows per half.
    __syncthreads();
    #pragma unroll
    for (int half = 0; half < 2; ++half) {
        #pragma unroll
        for (int tm = 0; tm < 4; ++tm)
            #pragma unroll
            for (int tn2 = 0; tn2 < 2; ++tn2) {
                int tn = half * 2 + tn2;
                int rl = tn2 * 16 + c;             // local token row
                *(f32x4*)(stage + rl * 2048 +
                          ((wave * 256 + tm * 64 + g * 16) ^ ((c & 7) << 4))) =
                    va[tm][tn];
            }
        __syncthreads();
        #pragma unroll
        for (int i = 0; i < 8; ++i) {
            int lin = i * 8192 + tid * 16;
            int rl = lin >> 11, off = lin & 2047;
            f32x4 v = *(const f32x4*)(stage + rl * 2048 + (off ^ ((rl & 7) << 4)));
            *(f32x4*)((char*)outblk + half * 65536 + lin) = v;
        }
        if (half == 0) __syncthreads();
    }
}

// ===========================================================================
// MAIN kernel: full attention for non-focused blocks.
// LDS: X 64KB + per-wave slots 64KB (slots reused as out staging).
// ===========================================================================
template<int WB16>
__global__ __launch_bounds__(512, 2) __attribute__((amdgpu_waves_per_eu(2, 2)))
void attn_main(const float* __restrict__ x,
               const float* __restrict__ w,
               const unsigned short* __restrict__ wb,
               const float* __restrict__ pb,
               const unsigned int* __restrict__ mk,
               float* __restrict__ out)
{
    const int bs = blockIdx.x;
    const int b  = bs >> 10;
    if (decode_mask(mk, b)) return;     // handled by attn_focus

    extern __shared__ char smem[];
    const int tid  = threadIdx.x;
    const int lane = tid & 63;
    const int wave = tid >> 6;          // head
    const int g    = lane >> 4;
    const int c    = lane & 15;

    const float* xblk   = x   + (size_t)bs * (64 * DIM);
    float*       outblk = out + (size_t)bs * (64 * DIM);
    char* slotW = smem + 65536 + wave * 8192;   // k -> attn
    char* slotX = smem + wave * 8192;           // q -> vT (after X retirement)
    char* stage = smem + 65536;

    const int RQ = wave * 4;
    const int RK = 32 + wave * 4;
    const int RV = 64 + wave * 4;

    // ---- X staging (prologue, 1 barrier) ----
    const int srow = tid >> 3;
    const int scp  = tid & 7;
    float4 sa[4], sb[4];
    auto loadc = [&](int cc, float4 (&st)[4]) {
        const float* gp = xblk + srow * DIM + cc * 128 + scp * 16;
        st[0] = *(const float4*)gp;
        st[1] = *(const float4*)(gp + 4);
        st[2] = *(const float4*)(gp + 8);
        st[3] = *(const float4*)(gp + 12);
    };
    auto writec = [&](int cc, float4 (&st)[4]) {
        int kb = cc * 256 + scp * 32;
        s16x8 v0, v1;
        v0[0] = f2bf(st[0].x); v0[1] = f2bf(st[0].y);
        v0[2] = f2bf(st[0].z); v0[3] = f2bf(st[0].w);
        v0[4] = f2bf(st[1].x); v0[5] = f2bf(st[1].y);
        v0[6] = f2bf(st[1].z); v0[7] = f2bf(st[1].w);
        v1[0] = f2bf(st[2].x); v1[1] = f2bf(st[2].y);
        v1[2] = f2bf(st[2].z); v1[3] = f2bf(st[2].w);
        v1[4] = f2bf(st[3].x); v1[5] = f2bf(st[3].y);
        v1[6] = f2bf(st[3].z); v1[7] = f2bf(st[3].w);
        *(s16x8*)(smem + xaddr(srow, kb))      = v0;
        *(s16x8*)(smem + xaddr(srow, kb + 16)) = v1;
    };
    loadc(0, sa); loadc(1, sb);
    writec(0, sa); loadc(2, sa);
    writec(1, sb); loadc(3, sb);
    writec(2, sa);
    writec(3, sb);
    __syncthreads();

    // ---- helpers ----
    auto wl = [&](s16x8 (&d)[4], int rb, int ks) {
        #pragma unroll
        for (int i = 0; i < 4; ++i) d[i] = wfragL<WB16>(wb, w, rb + i, ks, lane);
    };
    auto xf = [&](s16x8 (&a)[4], int ks) {
        #pragma unroll
        for (int tr = 0; tr < 4; ++tr)
            a[tr] = *(const s16x8*)(smem + xaddr(tr * 16 + c, ks * 64 + g * 16));
    };
    auto mm = [&](f32x4 (&acc)[4][4], s16x8 (&a)[4], s16x8 (&bfr)[4]) {
        #pragma unroll
        for (int tr = 0; tr < 4; ++tr)
            #pragma unroll
            for (int tc = 0; tc < 4; ++tc)
                acc[tr][tc] = __builtin_amdgcn_mfma_f32_16x16x32_bf16(
                                  a[tr], bfr[tc], acc[tr][tc], 0, 0, 0);
    };
    auto gtstep = [&](f32x4 (&acc)[4][4], int ks, const char* bA, const char* bB) {
        s16x8 a2[4], b2[4];
        #pragma unroll
        for (int tr = 0; tr < 4; ++tr)
            a2[tr] = *(const s16x8*)(bA + taddr(tr * 16 + c, ks * 64 + g * 16));
        #pragma unroll
        for (int tc = 0; tc < 4; ++tc)
            b2[tc] = *(const s16x8*)(bB + taddr(tc * 16 + c, ks * 64 + g * 16));
        mm(acc, a2, b2);
    };
    auto storetile = [&](char* buf, f32x4 (&acc)[4][4]) {
        #pragma unroll
        for (int tr = 0; tr < 4; ++tr)
            #pragma unroll
            for (int tc = 0; tc < 4; ++tc)
                #pragma unroll
                for (int r = 0; r < 4; ++r) {
                    int row = tr * 16 + g * 4 + r;
                    int col = tc * 16 + c;
                    *(short*)(buf + (row << 7) + ((col * 2) ^ ((row & 7) << 4))) =
                        f2bf(acc[tr][tc][r]);
                }
    };
    auto zacc = [&](f32x4 (&acc)[4][4]) {
        f32x4 z = {0.f, 0.f, 0.f, 0.f};
        #pragma unroll
        for (int tr = 0; tr < 4; ++tr)
            #pragma unroll
            for (int tc = 0; tc < 4; ++tc)
                acc[tr][tc] = z;
    };

    // ---- q,k projection: fully unrolled, W double-buffer prefetch ----
    f32x4 qa[4][4], ka[4][4];
    zacc(qa); zacc(ka);
    s16x8 qfA[4], qfB[4], kfA[4], kfB[4], af[4];
    wl(qfA, RQ, 0); wl(kfA, RK, 0);
    #define QK2(ks, CUR, NXT, PRE)                                     \
    {                                                                  \
        if (PRE) { wl(qf##NXT, RQ, (ks) + 1); wl(kf##NXT, RK, (ks) + 1); } \
        xf(af, ks);                                                    \
        mm(qa, af, qf##CUR);                                           \
        mm(ka, af, kf##CUR);                                           \
    }
    QK2(0, A, B, 1)  QK2(1, B, A, 1)  QK2(2, A, B, 1)  QK2(3, B, A, 1)
    QK2(4, A, B, 1)  QK2(5, B, A, 1)  QK2(6, A, B, 1)  QK2(7, B, A, 1)
    QK2(8, A, B, 1)  QK2(9, B, A, 1)  QK2(10, A, B, 1) QK2(11, B, A, 1)
    QK2(12, A, B, 1) QK2(13, B, A, 1) QK2(14, A, B, 1) QK2(15, B, A, 0)
    #undef QK2

    storetile(slotW, ka);               // free k (slot region, wave-private)

    // ---- vT = Wv . X^T, W prefetch ----
    f32x4 va[4][4];
    zacc(va);
    wl(qfA, RV, 0);                     // reuse qfA/qfB as v-frag buffers
    #define V2(ks, CUR, NXT, PRE)                       \
    {                                                   \
        if (PRE) wl(qf##NXT, RV, (ks) + 1);             \
        xf(af, ks);                                     \
        mm(va, qf##CUR, af);                            \
    }
    V2(0, A, B, 1)  V2(1, B, A, 1)  V2(2, A, B, 1)  V2(3, B, A, 1)
    V2(4, A, B, 1)  V2(5, B, A, 1)  V2(6, A, B, 1)  V2(7, B, A, 1)
    V2(8, A, B, 1)  V2(9, B, A, 1)  V2(10, A, B, 1) V2(11, B, A, 1)
    V2(12, A, B, 1) V2(13, B, A, 1) V2(14, A, B, 1) V2(15, B, A, 0)
    #undef V2

    __syncthreads();                    // X retirement: X region -> slots

    storetile(slotX, qa);               // q -> own X sub-slot

    // ---- sim = q . k^T ----
    f32x4 sm[4][4];
    zacc(sm);
    gtstep(sm, 0, slotX, slotW);
    gtstep(sm, 1, slotX, slotW);

    // ---- bias + softmax (in registers) ----
    const float* pbh = pb + wave * 4096;
    #pragma unroll
    for (int tr = 0; tr < 4; ++tr) {
        #pragma unroll
        for (int r = 0; r < 4; ++r) {
            const int i = tr * 16 + g * 4 + r;
            float v0 = sm[tr][0][r] + pbh[i * 64 +  0 + c];
            float v1 = sm[tr][1][r] + pbh[i * 64 + 16 + c];
            float v2 = sm[tr][2][r] + pbh[i * 64 + 32 + c];
            float v3 = sm[tr][3][r] + pbh[i * 64 + 48 + c];
            float mx = fmaxf(fmaxf(v0, v1), fmaxf(v2, v3));
            mx = fmaxf(mx, __shfl_xor(mx, 1));
            mx = fmaxf(mx, __shfl_xor(mx, 2));
            mx = fmaxf(mx, __shfl_xor(mx, 4));
            mx = fmaxf(mx, __shfl_xor(mx, 8));
            float p0 = __expf(v0 - mx);
            float p1 = __expf(v1 - mx);
            float p2 = __expf(v2 - mx);
            float p3 = __expf(v3 - mx);
            float s = p0 + p1 + p2 + p3;
            s += __shfl_xor(s, 1);
            s += __shfl_xor(s, 2);
            s += __shfl_xor(s, 4);
            s += __shfl_xor(s, 8);
            float rinv = 1.0f / s;
            sm[tr][0][r] = p0 * rinv;
            sm[tr][1][r] = p1 * rinv;
            sm[tr][2][r] = p2 * rinv;
            sm[tr][3][r] = p3 * rinv;
        }
    }

    storetile(slotW, sm);               // attn overwrites k
    storetile(slotX, va);               // vT overwrites q

    // ---- out = attn . v ----
    f32x4 oa[4][4];
    zacc(oa);
    gtstep(oa, 0, slotW, slotX);
    gtstep(oa, 1, slotW, slotX);

    // ---- coalesced epilogue: stage 32 rows at a time in slot region ----
    __syncthreads();                    // all waves done reading slots
    #pragma unroll
    for (int half = 0; half < 2; ++half) {
        #pragma unroll
        for (int trh = 0; trh < 2; ++trh) {
            int trg = half * 2 + trh;
            #pragma unroll
            for (int tc = 0; tc < 4; ++tc)
                #pragma unroll
                for (int r = 0; r < 4; ++r) {
                    int rl  = trh * 16 + g * 4 + r;
                    int col = wave * 64 + tc * 16 + c;
                    *(float*)(stage + rl * 2048 + ((col * 4) ^ ((rl & 7) << 4))) =
                        oa[trg][tc][r];
                }
        }
        __syncthreads();
        #pragma unroll
        for (int i = 0; i < 8; ++i) {
            int lin = i * 8192 + tid * 16;
            int rl = lin >> 11, off = lin & 2047;
            f32x4 v = *(const f32x4*)(stage + rl * 2048 + (off ^ ((rl & 7) << 4)));
            *(f32x4*)((char*)outblk + half * 65536 + lin) = v;
        }
        if (half == 0) __syncthreads();
    }
}

extern "C" void kernel_launch(void* const* d_in, const int* in_sizes, int n_in,
                              void* d_out, int out_size, void* d_ws, size_t ws_size,
                              hipStream_t stream)
{
    const float* x  = (const float*)d_in[0];
    const float* w  = (const float*)d_in[1];
    const float* pb = (const float*)d_in[2];
    const unsigned int* mk = (const unsigned int*)d_in[3];
    float* out = (float*)d_out;

    const int LDS_F = 81920;
    const int LDS_N = 131072;
    const size_t wbytes = (size_t)1536 * 512 * sizeof(unsigned short);

    if (ws_size >= wbytes) {
        unsigned short* wb = (unsigned short*)d_ws;
        conv_w<<<dim3(384), dim3(256), 0, stream>>>(w, wb);
        hipFuncSetAttribute(reinterpret_cast<const void*>(&attn_focus<1>),
                            hipFuncAttributeMaxDynamicSharedMemorySize, LDS_F);
        hipFuncSetAttribute(reinterpret_cast<const void*>(&attn_main<1>),
                            hipFuncAttributeMaxDynamicSharedMemorySize, LDS_N);
        attn_focus<1><<<dim3(2048), dim3(512), LDS_F, stream>>>(x, w, wb, mk, out);
        attn_main<1><<<dim3(2048), dim3(512), LDS_N, stream>>>(x, w, wb, pb, mk, out);
    } else {
        hipFuncSetAttribute(reinterpret_cast<const void*>(&attn_focus<0>),
                            hipFuncAttributeMaxDynamicSharedMemorySize, LDS_F);
        hipFuncSetAttribute(reinterpret_cast<const void*>(&attn_main<0>),
                            hipFuncAttributeMaxDynamicSharedMemorySize, LDS_N);
        attn_focus<0><<<dim3(2048), dim3(512), LDS_F, stream>>>(x, w, nullptr, mk, out);
        attn_main<0><<<dim3(2048), dim3(512), LDS_N, stream>>>(x, w, nullptr, pb, mk, out);
    }
}

// Round 4
// 322.496 us; speedup vs baseline: 1.5296x; 1.5296x over previous
//
#include <hip/hip_runtime.h>
#include <hip/hip_bf16.h>

// ---------------------------------------------------------------------------
// Round 4: 16-wave main kernel (dh-split projection => W read once per block,
// token-split attention), non-temporal x/out streams to keep W hot in L2,
// focused-batch lean kernel.
//   x:        (2,1024,64,512) f32
//   w_qkv:    (1536,512)      f32   (rows 0..511=Q, 512..1023=K, 1024..1535=V)
//   pos_bias: (8,64,64)       f32
//   mask:     (2,) bool/int
//   out:      (2,1024,64,512) f32
// ---------------------------------------------------------------------------

typedef __attribute__((ext_vector_type(4))) float f32x4;
typedef __attribute__((ext_vector_type(8))) short s16x8;

#define DIM 512

__device__ __forceinline__ short f2bf(float f) {
    unsigned int u = __builtin_bit_cast(unsigned int, f);
    u += 0x7fffu + ((u >> 16) & 1u);
    return (short)(u >> 16);
}

__device__ __forceinline__ f32x4 ntld4(const float* p) {
    return __builtin_nontemporal_load((const f32x4*)p);
}
__device__ __forceinline__ void ntst4(float* p, f32x4 v) {
    __builtin_nontemporal_store(v, (f32x4*)p);
}

__device__ __forceinline__ s16x8 pack8(f32x4 a, f32x4 b) {
    s16x8 v;
    v[0] = f2bf(a[0]); v[1] = f2bf(a[1]); v[2] = f2bf(a[2]); v[3] = f2bf(a[3]);
    v[4] = f2bf(b[0]); v[5] = f2bf(b[1]); v[6] = f2bf(b[2]); v[7] = f2bf(b[3]);
    return v;
}

__device__ __forceinline__ int xaddr(int row, int kb) {   // X: 64x512 bf16, 1024B rows
    return (row << 10) + (kb ^ ((row & 7) << 4));
}
__device__ __forceinline__ int taddr(int row, int kb) {   // 64x64 bf16 tile, 128B rows
    return (row << 7) + (kb ^ ((row & 7) << 4));
}

// W pre-swizzle: 16B fragment chunk index = (rowblk*16 + ks)*64 + lane
// (wave's fragment load = one contiguous 1 KiB read). q-scale folded into Wq.
__global__ void conv_w(const float* __restrict__ w, unsigned short* __restrict__ wb) {
    int gid  = blockIdx.x * 256 + threadIdx.x;       // 0 .. 98303
    int lane = gid & 63;
    int ks   = (gid >> 6) & 15;
    int rowblk = gid >> 10;
    int row = rowblk * 16 + (lane & 15);
    int col = ks * 32 + (lane >> 4) * 8;
    const float* p = w + (size_t)row * DIM + col;
    f32x4 a = *(const f32x4*)p;
    f32x4 b = *(const f32x4*)(p + 4);
    float sc = (row < 512) ? 0.125f : 1.0f;
    a *= sc; b *= sc;
    *(s16x8*)(wb + (size_t)gid * 8) = pack8(a, b);
}

template<int WB16>
__device__ __forceinline__ s16x8 wfragL(const unsigned short* __restrict__ wb,
                                        const float* __restrict__ w,
                                        int rowblk, int ks, int lane) {
    if constexpr (WB16) {
        return *(const s16x8*)(wb + ((size_t)(rowblk * 16 + ks) * 64 + lane) * 8);
    } else {
        int row = rowblk * 16 + (lane & 15);
        int col = ks * 32 + (lane >> 4) * 8;
        const float* p = w + (size_t)row * DIM + col;
        f32x4 u0 = *(const f32x4*)p;
        f32x4 u1 = *(const f32x4*)(p + 4);
        float sc = (row < 512) ? 0.125f : 1.0f;
        u0 *= sc; u1 *= sc;
        return pack8(u0, u1);
    }
}

__device__ __forceinline__ bool decode_mask(const unsigned int* mk, int b) {
    unsigned int m0 = mk[0], m1 = mk[1];
    if (m0 <= 1u && m1 <= 1u) return ((b == 0) ? m0 : m1) != 0u;
    return ((const unsigned char*)mk)[b] != 0;
}

// generic C-tile -> LDS 64x64 bf16 tile (taddr layout) scatter store
template<int R, int C>
__device__ __forceinline__ void store_tile(char* buf, f32x4 (&acc)[R][C],
                                           int rowbase, int colbase, int g, int c) {
    #pragma unroll
    for (int tr = 0; tr < R; ++tr)
        #pragma unroll
        for (int tc = 0; tc < C; ++tc)
            #pragma unroll
            for (int r = 0; r < 4; ++r) {
                int row = rowbase + tr * 16 + g * 4 + r;
                int col = colbase + tc * 16 + c;
                *(short*)(buf + (row << 7) + ((col * 2) ^ ((row & 7) << 4))) =
                    f2bf(acc[tr][tc][r]);
            }
}

// ===========================================================================
// FOCUSED kernel: eye mask => attn = I => out = v = X . Wv^T.
// LDS: 2 x 8KB X chunk double-buffer + 64KB out staging = 80KB -> 2 blocks/CU.
// ===========================================================================
template<int WB16>
__global__ __launch_bounds__(512, 4)
void attn_focus(const float* __restrict__ x,
                const float* __restrict__ w,
                const unsigned short* __restrict__ wb,
                const unsigned int* __restrict__ mk,
                float* __restrict__ out)
{
    const int bs = blockIdx.x;
    const int b  = bs >> 10;
    if (!decode_mask(mk, b)) return;

    extern __shared__ char smem[];
    const int tid  = threadIdx.x;
    const int lane = tid & 63;
    const int wave = tid >> 6;          // head
    const int g    = lane >> 4;
    const int c    = lane & 15;

    const float* xblk   = x   + (size_t)bs * (64 * DIM);
    float*       outblk = out + (size_t)bs * (64 * DIM);
    char* stage = smem + 16384;
    const int RV = 64 + wave * 4;

    auto fld = [&](int kk, f32x4 (&st)[2]) {
        const float* gp = xblk + (tid >> 3) * DIM + kk * 64 + (tid & 7) * 8;
        st[0] = ntld4(gp);
        st[1] = ntld4(gp + 4);
    };
    auto fwr = [&](int p, f32x4 (&st)[2]) {
        int row = tid >> 3, cg = tid & 7;
        *(s16x8*)(smem + p * 8192 + (row << 7) + ((cg * 16) ^ ((row & 7) << 4))) =
            pack8(st[0], st[1]);
    };
    auto xfc = [&](s16x8 (&a)[4], int p, int ksl) {
        #pragma unroll
        for (int tc = 0; tc < 4; ++tc) {
            int row = tc * 16 + c;
            a[tc] = *(const s16x8*)(smem + p * 8192 + (row << 7) +
                                    ((ksl * 64 + g * 16) ^ ((row & 7) << 4)));
        }
    };
    auto wl = [&](s16x8 (&d)[4], int ks) {
        #pragma unroll
        for (int i = 0; i < 4; ++i) d[i] = wfragL<WB16>(wb, w, RV + i, ks, lane);
    };
    auto mmT = [&](f32x4 (&acc)[4][4], s16x8 (&a)[4], s16x8 (&bfr)[4]) {
        #pragma unroll
        for (int tr = 0; tr < 4; ++tr)
            #pragma unroll
            for (int tc = 0; tc < 4; ++tc)
                acc[tr][tc] = __builtin_amdgcn_mfma_f32_16x16x32_bf16(
                                  a[tr], bfr[tc], acc[tr][tc], 0, 0, 0);
    };

    f32x4 va[4][4];
    {
        f32x4 z = {0.f, 0.f, 0.f, 0.f};
        #pragma unroll
        for (int i = 0; i < 4; ++i)
            #pragma unroll
            for (int j = 0; j < 4; ++j) va[i][j] = z;
    }

    f32x4 sA[2], sB[2];
    s16x8 wf[4], af[4];

    fld(0, sA); fwr(0, sA);
    __syncthreads();

    #define FSTEP(kk, SN)                                              \
    {                                                                  \
        if ((kk) < 7) fld((kk) + 1, s##SN);                            \
        wl(wf, 2 * (kk));                                              \
        xfc(af, (kk) & 1, 0);                                          \
        mmT(va, wf, af);                                               \
        wl(wf, 2 * (kk) + 1);                                          \
        xfc(af, (kk) & 1, 1);                                          \
        mmT(va, wf, af);                                               \
        if ((kk) < 7) { fwr(((kk) + 1) & 1, s##SN); __syncthreads(); } \
    }
    FSTEP(0, B) FSTEP(1, A) FSTEP(2, B) FSTEP(3, A)
    FSTEP(4, B) FSTEP(5, A) FSTEP(6, B) FSTEP(7, A)
    #undef FSTEP

    // epilogue: va[tm][tn] = vT[dh=tm*16+g*4+r][tok=tn*16+c]; f32x4 spans dh.
    __syncthreads();
    #pragma unroll
    for (int half = 0; half < 2; ++half) {
        #pragma unroll
        for (int tm = 0; tm < 4; ++tm)
            #pragma unroll
            for (int tn2 = 0; tn2 < 2; ++tn2) {
                int tn = half * 2 + tn2;
                int rl = tn2 * 16 + c;             // local token row
                *(f32x4*)(stage + rl * 2048 +
                          ((wave * 256 + tm * 64 + g * 16) ^ ((c & 7) << 4))) =
                    va[tm][tn];
            }
        __syncthreads();
        #pragma unroll
        for (int i = 0; i < 8; ++i) {
            int lin = i * 8192 + tid * 16;
            int rl = lin >> 11, off = lin & 2047;
            f32x4 v = *(const f32x4*)(stage + rl * 2048 + (off ^ ((rl & 7) << 4)));
            ntst4((float*)((char*)outblk + half * 65536 + lin), v);
        }
        if (half == 0) __syncthreads();
    }
}

// ===========================================================================
// MAIN kernel: 1024 threads = 16 waves; wave = (head, half).
// Projection dh-split (each W row read once/block); attention token-split.
// LDS: A[0,64K): X -> k -> attn ; B[64K,128K): q -> vT ; all: out staging.
// ===========================================================================
template<int WB16>
__global__ __launch_bounds__(1024, 4)
void attn_main(const float* __restrict__ x,
               const float* __restrict__ w,
               const unsigned short* __restrict__ wb,
               const float* __restrict__ pb,
               const unsigned int* __restrict__ mk,
               float* __restrict__ out)
{
    const int bs = blockIdx.x;
    const int b  = bs >> 10;
    if (decode_mask(mk, b)) return;     // handled by attn_focus

    extern __shared__ char smem[];
    const int tid  = threadIdx.x;
    const int lane = tid & 63;
    const int wave = tid >> 6;          // 0..15
    const int head = wave >> 1;
    const int hw2  = wave & 1;          // dh-half (proj) / token-half (attn)
    const int g    = lane >> 4;
    const int c    = lane & 15;

    const float* xblk   = x   + (size_t)bs * (64 * DIM);
    float*       outblk = out + (size_t)bs * (64 * DIM);
    char* slotA = smem + head * 8192;           // (X) -> k -> attn
    char* slotB = smem + 65536 + head * 8192;   // q -> vT

    const int RQ = head * 4 + 2 * hw2;          // Wq rowblks (dh-half)
    const int RK = 32 + head * 4 + 2 * hw2;
    const int RV = 64 + head * 4 + 2 * hw2;

    // ---- X staging: 64x512 f32 -> bf16 swizzled LDS (regionA), nt loads ----
    {
        int row = tid >> 4, cp = tid & 15;
        const float* gp = xblk + row * DIM + cp * 32;
        f32x4 f0 = ntld4(gp),      f1 = ntld4(gp + 4);
        f32x4 f2 = ntld4(gp + 8),  f3 = ntld4(gp + 12);
        f32x4 f4 = ntld4(gp + 16), f5 = ntld4(gp + 20);
        f32x4 f6 = ntld4(gp + 24), f7 = ntld4(gp + 28);
        *(s16x8*)(smem + xaddr(row, cp * 64))      = pack8(f0, f1);
        *(s16x8*)(smem + xaddr(row, cp * 64 + 16)) = pack8(f2, f3);
        *(s16x8*)(smem + xaddr(row, cp * 64 + 32)) = pack8(f4, f5);
        *(s16x8*)(smem + xaddr(row, cp * 64 + 48)) = pack8(f6, f7);
    }
    __syncthreads();                                         // (1)

    auto zacc42 = [&](f32x4 (&a)[4][2]) {
        f32x4 z = {0.f, 0.f, 0.f, 0.f};
        #pragma unroll
        for (int i = 0; i < 4; ++i) { a[i][0] = z; a[i][1] = z; }
    };
    auto zacc24 = [&](f32x4 (&a)[2][4]) {
        f32x4 z = {0.f, 0.f, 0.f, 0.f};
        #pragma unroll
        for (int i = 0; i < 2; ++i)
            #pragma unroll
            for (int j = 0; j < 4; ++j) a[i][j] = z;
    };

    // ---- q,k projection (dh-split): C[tok, dh-half] ----
    f32x4 qa[4][2], ka[4][2];
    zacc42(qa); zacc42(ka);
    #pragma unroll
    for (int ks = 0; ks < 16; ++ks) {
        s16x8 af[4], wq[2], wk[2];
        wq[0] = wfragL<WB16>(wb, w, RQ,     ks, lane);
        wq[1] = wfragL<WB16>(wb, w, RQ + 1, ks, lane);
        wk[0] = wfragL<WB16>(wb, w, RK,     ks, lane);
        wk[1] = wfragL<WB16>(wb, w, RK + 1, ks, lane);
        #pragma unroll
        for (int t = 0; t < 4; ++t)
            af[t] = *(const s16x8*)(smem + xaddr(t * 16 + c, ks * 64 + g * 16));
        #pragma unroll
        for (int tr = 0; tr < 4; ++tr) {
            qa[tr][0] = __builtin_amdgcn_mfma_f32_16x16x32_bf16(af[tr], wq[0], qa[tr][0], 0, 0, 0);
            qa[tr][1] = __builtin_amdgcn_mfma_f32_16x16x32_bf16(af[tr], wq[1], qa[tr][1], 0, 0, 0);
            ka[tr][0] = __builtin_amdgcn_mfma_f32_16x16x32_bf16(af[tr], wk[0], ka[tr][0], 0, 0, 0);
            ka[tr][1] = __builtin_amdgcn_mfma_f32_16x16x32_bf16(af[tr], wk[1], ka[tr][1], 0, 0, 0);
        }
    }
    store_tile<4, 2>(slotB, qa, 0, hw2 * 32, g, c);          // q -> B

    // ---- vT projection (dh-split rows): C[dh-half, tok] ----
    f32x4 va[2][4];
    zacc24(va);
    #pragma unroll
    for (int ks = 0; ks < 16; ++ks) {
        s16x8 af[4], wv[2];
        wv[0] = wfragL<WB16>(wb, w, RV,     ks, lane);
        wv[1] = wfragL<WB16>(wb, w, RV + 1, ks, lane);
        #pragma unroll
        for (int t = 0; t < 4; ++t)
            af[t] = *(const s16x8*)(smem + xaddr(t * 16 + c, ks * 64 + g * 16));
        #pragma unroll
        for (int tc = 0; tc < 4; ++tc) {
            va[0][tc] = __builtin_amdgcn_mfma_f32_16x16x32_bf16(wv[0], af[tc], va[0][tc], 0, 0, 0);
            va[1][tc] = __builtin_amdgcn_mfma_f32_16x16x32_bf16(wv[1], af[tc], va[1][tc], 0, 0, 0);
        }
    }
    __syncthreads();                                         // (2) X dead, q visible

    store_tile<4, 2>(slotA, ka, 0, hw2 * 32, g, c);          // k -> A (over X)
    __syncthreads();                                         // (3)

    // ---- sim = q . k^T (token-split rows) ----
    f32x4 sm[2][4];
    zacc24(sm);
    #pragma unroll
    for (int ks = 0; ks < 2; ++ks) {
        s16x8 aq[2], bk[4];
        #pragma unroll
        for (int i = 0; i < 2; ++i)
            aq[i] = *(const s16x8*)(slotB + taddr((2 * hw2 + i) * 16 + c, ks * 64 + g * 16));
        #pragma unroll
        for (int j = 0; j < 4; ++j)
            bk[j] = *(const s16x8*)(slotA + taddr(j * 16 + c, ks * 64 + g * 16));
        #pragma unroll
        for (int tr = 0; tr < 2; ++tr)
            #pragma unroll
            for (int tc = 0; tc < 4; ++tc)
                sm[tr][tc] = __builtin_amdgcn_mfma_f32_16x16x32_bf16(
                                 aq[tr], bk[tc], sm[tr][tc], 0, 0, 0);
    }

    // ---- bias + softmax (rows i = 32*hw2 + tr*16 + g*4 + r) ----
    const float* pbh = pb + head * 4096;
    #pragma unroll
    for (int tr = 0; tr < 2; ++tr) {
        #pragma unroll
        for (int r = 0; r < 4; ++r) {
            const int i = 32 * hw2 + tr * 16 + g * 4 + r;
            float v0 = sm[tr][0][r] + pbh[i * 64 +  0 + c];
            float v1 = sm[tr][1][r] + pbh[i * 64 + 16 + c];
            float v2 = sm[tr][2][r] + pbh[i * 64 + 32 + c];
            float v3 = sm[tr][3][r] + pbh[i * 64 + 48 + c];
            float mx = fmaxf(fmaxf(v0, v1), fmaxf(v2, v3));
            mx = fmaxf(mx, __shfl_xor(mx, 1));
            mx = fmaxf(mx, __shfl_xor(mx, 2));
            mx = fmaxf(mx, __shfl_xor(mx, 4));
            mx = fmaxf(mx, __shfl_xor(mx, 8));
            float p0 = __expf(v0 - mx);
            float p1 = __expf(v1 - mx);
            float p2 = __expf(v2 - mx);
            float p3 = __expf(v3 - mx);
            float s = p0 + p1 + p2 + p3;
            s += __shfl_xor(s, 1);
            s += __shfl_xor(s, 2);
            s += __shfl_xor(s, 4);
            s += __shfl_xor(s, 8);
            float rinv = 1.0f / s;
            sm[tr][0][r] = p0 * rinv;
            sm[tr][1][r] = p1 * rinv;
            sm[tr][2][r] = p2 * rinv;
            sm[tr][3][r] = p3 * rinv;
        }
    }
    __syncthreads();                                         // (4) q,k reads done

    store_tile<2, 4>(slotA, sm, 32 * hw2, 0, g, c);          // attn -> A
    store_tile<2, 4>(slotB, va, 32 * hw2, 0, g, c);          // vT   -> B
    __syncthreads();                                         // (5)

    // ---- oT = vT . attn^T : C[dh, tok-half] ----
    f32x4 ot[4][2];
    zacc42(ot);
    #pragma unroll
    for (int ks = 0; ks < 2; ++ks) {
        s16x8 av[4], ba[2];
        #pragma unroll
        for (int i = 0; i < 4; ++i)
            av[i] = *(const s16x8*)(slotB + taddr(i * 16 + c, ks * 64 + g * 16));
        #pragma unroll
        for (int j = 0; j < 2; ++j)
            ba[j] = *(const s16x8*)(slotA + taddr((2 * hw2 + j) * 16 + c, ks * 64 + g * 16));
        #pragma unroll
        for (int tr = 0; tr < 4; ++tr)
            #pragma unroll
            for (int tc = 0; tc < 2; ++tc)
                ot[tr][tc] = __builtin_amdgcn_mfma_f32_16x16x32_bf16(
                                 av[tr], ba[tc], ot[tr][tc], 0, 0, 0);
    }
    __syncthreads();                                         // (6) PV reads done

    // ---- out staging: ot[tr][tc] = out[tok=32*hw2+tc*16+c][dh=tr*16+g*4+r] ----
    #pragma unroll
    for (int tr = 0; tr < 4; ++tr)
        #pragma unroll
        for (int tc = 0; tc < 2; ++tc) {
            int rl   = 32 * hw2 + tc * 16 + c;                // token row
            int colb = head * 256 + tr * 64 + g * 16;         // dh byte offset
            *(f32x4*)(smem + rl * 2048 + (colb ^ ((rl & 7) << 4))) = ot[tr][tc];
        }
    __syncthreads();                                         // (7)

    #pragma unroll
    for (int i = 0; i < 8; ++i) {
        int lin = i * 16384 + tid * 16;
        int rl = lin >> 11, off = lin & 2047;
        f32x4 v = *(const f32x4*)(smem + rl * 2048 + (off ^ ((rl & 7) << 4)));
        ntst4((float*)((char*)outblk + lin), v);
    }
}

extern "C" void kernel_launch(void* const* d_in, const int* in_sizes, int n_in,
                              void* d_out, int out_size, void* d_ws, size_t ws_size,
                              hipStream_t stream)
{
    const float* x  = (const float*)d_in[0];
    const float* w  = (const float*)d_in[1];
    const float* pb = (const float*)d_in[2];
    const unsigned int* mk = (const unsigned int*)d_in[3];
    float* out = (float*)d_out;

    const int LDS_F = 81920;
    const int LDS_N = 131072;
    const size_t wbytes = (size_t)1536 * 512 * sizeof(unsigned short);

    if (ws_size >= wbytes) {
        unsigned short* wb = (unsigned short*)d_ws;
        conv_w<<<dim3(384), dim3(256), 0, stream>>>(w, wb);
        hipFuncSetAttribute(reinterpret_cast<const void*>(&attn_focus<1>),
                            hipFuncAttributeMaxDynamicSharedMemorySize, LDS_F);
        hipFuncSetAttribute(reinterpret_cast<const void*>(&attn_main<1>),
                            hipFuncAttributeMaxDynamicSharedMemorySize, LDS_N);
        attn_focus<1><<<dim3(2048), dim3(512), LDS_F, stream>>>(x, w, wb, mk, out);
        attn_main<1><<<dim3(2048), dim3(1024), LDS_N, stream>>>(x, w, wb, pb, mk, out);
    } else {
        hipFuncSetAttribute(reinterpret_cast<const void*>(&attn_focus<0>),
                            hipFuncAttributeMaxDynamicSharedMemorySize, LDS_F);
        hipFuncSetAttribute(reinterpret_cast<const void*>(&attn_main<0>),
                            hipFuncAttributeMaxDynamicSharedMemorySize, LDS_N);
        attn_focus<0><<<dim3(2048), dim3(512), LDS_F, stream>>>(x, w, nullptr, mk, out);
        attn_main<0><<<dim3(2048), dim3(1024), LDS_N, stream>>>(x, w, nullptr, pb, mk, out);
    }
}